// Round 7
// baseline (124.319 us; speedup 1.0000x reference)
//
#include <hip/hip_runtime.h>
#include <hip/hip_bf16.h>
#include <math.h>

#define CIN   64
#define COUT  32
#define K1V   17
#define HV    4
#define RPB   64          // rows per proj block
#define XPAD  68          // LDS row stride (floats)
#define BTILE 6           // bt slices per gcn block

typedef float v4f __attribute__((ext_vector_type(4)));  // clang vector: OK for nontemporal builtins

// Kernel A: xp[r,o] = sum_i x[r,i]*W[o,i] + b[o]
// Stage 64 rows in LDS (coalesced, nontemporal: x is read-once). Wave w owns
// output channels w*8..w*8+7 (wave-uniform -> W/b ride the scalar pipe as
// s_loads). lane = row -> x fragments via ds_read_b128.
__global__ __launch_bounds__(256) void proj_kernel(
    const float* __restrict__ x, const float* __restrict__ W,
    const float* __restrict__ b, float* __restrict__ xp, long nrows) {
  __shared__ float Xl[RPB * XPAD];   // 17408 B
  int tid = threadIdx.x;
  long r0 = (long)blockIdx.x * RPB;

  const v4f* xg = (const v4f*)(x + r0 * CIN);
#pragma unroll
  for (int s = 0; s < 4; ++s) {
    int fi  = tid + s * 256;          // float4 index in tile
    int row = fi >> 4;
    int col = (fi & 15) << 2;
    v4f v = __builtin_nontemporal_load(&xg[fi]);
    *(v4f*)&Xl[row * XPAD + col] = v;
  }
  __syncthreads();

  int wv   = __builtin_amdgcn_readfirstlane(tid >> 6);  // wave id 0..3 (SGPR)
  int lane = tid & 63;                                  // row within tile
  long r = r0 + lane;
  if (r >= nrows) return;

  const float* Wb = W + wv * 8 * CIN;   // uniform base
  float acc[8];
#pragma unroll
  for (int oo = 0; oo < 8; ++oo) acc[oo] = b[wv * 8 + oo];

#pragma unroll
  for (int j = 0; j < CIN / 4; ++j) {
    v4f xv = *(const v4f*)&Xl[lane * XPAD + j * 4];
#pragma unroll
    for (int oo = 0; oo < 8; ++oo) {
      v4f w4 = *(const v4f*)(Wb + oo * CIN + j * 4);  // s_load_dwordx4
      acc[oo] = fmaf(xv.x, w4.x,
                fmaf(xv.y, w4.y,
                fmaf(xv.z, w4.z,
                fmaf(xv.w, w4.w, acc[oo]))));
    }
  }

  float* op = xp + r * COUT + wv * 8;   // xp stays cached for gcn
  v4f lo = { acc[0], acc[1], acc[2], acc[3] };
  v4f hi = { acc[4], acc[5], acc[6], acc[7] };
  *(v4f*)op       = lo;
  *(v4f*)(op + 4) = hi;
}

// Kernel C: block = 8 nodes x 4 heads x 8 channel-quads = 256 threads.
// Each thread computes 4 consecutive channels of one (node, head) for 6 bt
// slices: gathers are float4 (one b128 per 16 outputs per k), stores are one
// b128 nt-store. Table (w, idx, dist_agg) built once per block, w[17]/off[17]
// hoisted to registers.
__global__ __launch_bounds__(256, 4) void gcn_kernel(
    const float* __restrict__ xp,    // (BT, N, 32)
    const float* __restrict__ dist,  // (N, K1)
    const int*   __restrict__ nn,    // (N, K1)
    float* __restrict__ out,         // (BT, N, H, 32)
    int BT, int N) {
  __shared__ float wl[8][K1V][HV];
  __shared__ float dl[8][K1V];
  __shared__ int   nl[8][K1V];
  __shared__ float dagl[8][HV];

  int tid = threadIdx.x;
  int n0  = blockIdx.x * 8;
  int bt0 = blockIdx.y * BTILE;

  if (tid < 8 * K1V) {        // 136 builder threads
    int l = tid / K1V, k = tid % K1V;
    int n_ = n0 + l;
    float w0 = 0, w1 = 0, w2 = 0, w3 = 0, dc = 0;
    int idx = 0;
    if (n_ < N) {
      float d = dist[(long)n_ * K1V + k];
      idx = nn[(long)n_ * K1V + k];
      float d2 = d * d;
      w0 = __expf(-d2 * 0.25f);
      w1 = __expf(-d2 * 0.50f);
      w2 = __expf(-d2 * 0.75f);
      w3 = __expf(-d2);
      if (idx == -1) { w0 = w1 = w2 = w3 = 0.0f; }
      if (w0 < 1e-5f) w0 = 0.0f;
      if (w1 < 1e-5f) w1 = 0.0f;
      if (w2 < 1e-5f) w2 = 0.0f;
      if (w3 < 1e-5f) w3 = 0.0f;
      dc = isinf(d) ? 0.0f : d;
      if (idx < 0 || idx >= N) idx = 0;   // its w==0; safe address
    }
    wl[l][k][0] = w0; wl[l][k][1] = w1; wl[l][k][2] = w2; wl[l][k][3] = w3;
    dl[l][k] = dc; nl[l][k] = idx;
  }
  __syncthreads();

  if (tid < 8 * HV) {         // fold dist_agg once per (node, head)
    int l = tid >> 2, h = tid & 3;
    float s = 0.0f;
#pragma unroll
    for (int k = 0; k < K1V; ++k) s = fmaf(wl[l][k][h], dl[l][k], s);
    dagl[l][h] = s;
  }
  __syncthreads();

  int cg = tid & 7;           // channel quad (4 floats)
  int h  = (tid >> 3) & 3;    // head
  int ln = tid >> 5;          // local node
  int n  = n0 + ln;
  if (n >= N) return;

  // hoist per-thread weights + gather offsets (float-index) into registers
  float wk[K1V];
  int   off[K1V];
#pragma unroll
  for (int k = 0; k < K1V; ++k) {
    wk[k]  = wl[ln][k][h];
    off[k] = nl[ln][k] * COUT + cg * 4;
  }
  float dag = dagl[ln][h];

  for (int t = 0; t < BTILE; ++t) {
    int bt = bt0 + t;
    if (bt >= BT) break;
    const float* base = xp + (size_t)bt * N * COUT;
    v4f a = { dag, dag, dag, dag };
#pragma unroll
    for (int k = 0; k < K1V; ++k) {
      v4f v = *(const v4f*)(base + off[k]);
      a.x = fmaf(wk[k], v.x, a.x);
      a.y = fmaf(wk[k], v.y, a.y);
      a.z = fmaf(wk[k], v.z, a.z);
      a.w = fmaf(wk[k], v.w, a.w);
    }
    v4f* ob = (v4f*)(out + (((size_t)bt * N + n) * HV + h) * COUT + cg * 4);
    __builtin_nontemporal_store(a, ob);
  }
}

extern "C" void kernel_launch(void* const* d_in, const int* in_sizes, int n_in,
                              void* d_out, int out_size, void* d_ws, size_t ws_size,
                              hipStream_t stream) {
  const float* x    = (const float*)d_in[0];
  const float* W    = (const float*)d_in[1];
  const float* b    = (const float*)d_in[2];
  const float* dist = (const float*)d_in[3];
  const int*   nn   = (const int*)d_in[4];
  float* out = (float*)d_out;
  float* xp  = (float*)d_ws;   // (BT, N, 32) fp32 = 30.72 MB

  int  N  = in_sizes[4] / K1V;                 // 10000
  long M  = (long)in_sizes[0] / CIN;           // BT * N = 240000
  int  BT = (int)(M / N);                      // 24

  proj_kernel<<<(int)((M + RPB - 1) / RPB), 256, 0, stream>>>(x, W, b, xp, M);

  dim3 grid((N + 7) / 8, (BT + BTILE - 1) / BTILE);   // 1250 x 4
  gcn_kernel<<<grid, 256, 0, stream>>>(xp, dist, nn, out, BT, N);
}

// Round 8
// 91.315 us; speedup vs baseline: 1.3614x; 1.3614x over previous
//
#include <hip/hip_runtime.h>
#include <hip/hip_bf16.h>
#include <math.h>

#define CIN   64
#define COUT  32
#define K1V   17
#define HV    4
#define RPB   64          // rows per proj block
#define XPAD  68          // LDS x-row stride (floats): lanes cover all 8 quad-bank groups -> conflict-free b128

typedef float v4f __attribute__((ext_vector_type(4)));
typedef unsigned short u16;
typedef u16 v8s __attribute__((ext_vector_type(8)));

__device__ __forceinline__ u16 f2bf(float f) {          // RNE float->bf16
  unsigned u = __builtin_bit_cast(unsigned, f);
  unsigned r = 0x7FFFu + ((u >> 16) & 1u);
  return (u16)((u + r) >> 16);
}
__device__ __forceinline__ float bf2f(u16 h) {
  unsigned u = ((unsigned)h) << 16;
  return __builtin_bit_cast(float, u);
}

// Kernel T: precompute per-(n,k) head weights w[4], safe gather idx, and
// per-(n,h) dist_agg. Runs once (amortizes the 24x redundant rebuild).
__global__ __launch_bounds__(256) void table_kernel(
    const float* __restrict__ dist, const int* __restrict__ nn,
    float* __restrict__ wtab,   // (N*K1, 4)
    int*   __restrict__ itab,   // (N*K1)
    float* __restrict__ dagtab, // (N, 4)
    int N) {
  __shared__ float wl[8][K1V][HV];
  __shared__ float dl[8][K1V];
  int tid = threadIdx.x;
  int n0  = blockIdx.x * 8;

  if (tid < 8 * K1V) {
    int l = tid / K1V, k = tid % K1V;
    int n_ = n0 + l;
    float w0 = 0, w1 = 0, w2 = 0, w3 = 0, dc = 0;
    int idx = 0;
    if (n_ < N) {
      long  gi = (long)n_ * K1V + k;
      float d  = dist[gi];
      idx = nn[gi];
      float d2 = d * d;
      w0 = __expf(-d2 * 0.25f);
      w1 = __expf(-d2 * 0.50f);
      w2 = __expf(-d2 * 0.75f);
      w3 = __expf(-d2);
      if (idx == -1) { w0 = w1 = w2 = w3 = 0.0f; }
      if (w0 < 1e-5f) w0 = 0.0f;
      if (w1 < 1e-5f) w1 = 0.0f;
      if (w2 < 1e-5f) w2 = 0.0f;
      if (w3 < 1e-5f) w3 = 0.0f;
      dc = isinf(d) ? 0.0f : d;
      if (idx < 0 || idx >= N) idx = 0;   // its w==0; safe address
      v4f w4 = { w0, w1, w2, w3 };
      *(v4f*)&wtab[gi * 4] = w4;
      itab[gi] = idx;
    }
    wl[l][k][0] = w0; wl[l][k][1] = w1; wl[l][k][2] = w2; wl[l][k][3] = w3;
    dl[l][k] = dc;
  }
  __syncthreads();

  if (tid < 8 * HV) {
    int l = tid >> 2, h = tid & 3;
    int n_ = n0 + l;
    if (n_ < N) {
      float s = 0.0f;
#pragma unroll
      for (int k = 0; k < K1V; ++k) s = fmaf(wl[l][k][h], dl[l][k], s);
      dagtab[(long)n_ * HV + h] = s;
    }
  }
}

// Kernel A: xp16[r,o] = bf16( sum_i x[r,i]*W[o,i] + b[o] )
// W+b AND the 64-row x tile staged in LDS. Wave w owns outs [8w,8w+8):
// W reads are wave-uniform -> LDS broadcast (no VMEM W stream, no s_load
// guessing). Compute fp32, store one 16B bf16x8 per thread.
__global__ __launch_bounds__(256) void proj_kernel(
    const float* __restrict__ x, const float* __restrict__ W,
    const float* __restrict__ b, u16* __restrict__ xp, long nrows) {
  __shared__ float Xl[RPB * XPAD];   // 17408 B
  __shared__ float Wl[COUT * CIN];   // 8192 B
  __shared__ float bl[COUT];
  int tid = threadIdx.x;
  long r0 = (long)blockIdx.x * RPB;

  {  // stage W (512 float4) + b
    const v4f* wg = (const v4f*)W;
    v4f* ws = (v4f*)Wl;
    ws[tid]       = wg[tid];
    ws[tid + 256] = wg[tid + 256];
    if (tid < COUT) bl[tid] = b[tid];
  }
  {  // stage x tile (1024 float4)
    const v4f* xg = (const v4f*)(x + r0 * CIN);
#pragma unroll
    for (int s = 0; s < 4; ++s) {
      int fi  = tid + s * 256;
      int row = fi >> 4;
      int col = (fi & 15) << 2;
      *(v4f*)&Xl[row * XPAD + col] = xg[fi];
    }
  }
  __syncthreads();

  int wv   = __builtin_amdgcn_readfirstlane(tid >> 6);  // wave id (SGPR)
  int lane = tid & 63;
  long r = r0 + lane;
  if (r >= nrows) return;

  float acc[8];
#pragma unroll
  for (int oo = 0; oo < 8; ++oo) acc[oo] = bl[wv * 8 + oo];

#pragma unroll
  for (int j = 0; j < CIN / 4; ++j) {
    v4f xv = *(const v4f*)&Xl[lane * XPAD + j * 4];
#pragma unroll
    for (int oo = 0; oo < 8; ++oo) {
      v4f w4 = *(const v4f*)&Wl[(wv * 8 + oo) * CIN + j * 4];  // uniform -> broadcast
      acc[oo] = fmaf(xv.x, w4.x,
                fmaf(xv.y, w4.y,
                fmaf(xv.z, w4.z,
                fmaf(xv.w, w4.w, acc[oo]))));
    }
  }

  v8s pk;
#pragma unroll
  for (int oo = 0; oo < 8; ++oo) pk[oo] = f2bf(acc[oo]);
  *(v8s*)(xp + r * COUT + wv * 8) = pk;   // one 16B store
}

// Kernel C (R5 structure): grid (node_groups, BT), x fastest -> co-resident
// blocks share one 640KB bf16 slice (L2-hot). Stage precomputed table; each
// thread owns (node, ch), all 4 heads; 17 scalar bf16 gathers; nt stores.
__global__ __launch_bounds__(256) void gcn_kernel(
    const u16*   __restrict__ xp,     // (BT, N, 32) bf16
    const float* __restrict__ wtab,   // (N*K1, 4)
    const int*   __restrict__ itab,   // (N*K1)
    const float* __restrict__ dagtab, // (N, 4)
    float* __restrict__ out,          // (BT, N, H, 32)
    int N) {
  __shared__ float wl[8][K1V][HV];    // 2176 B
  __shared__ int   nl[8][K1V];
  __shared__ float dagl[8][HV];

  int tid = threadIdx.x;
  int bt  = blockIdx.y;
  int n0  = blockIdx.x * 8;

  if (tid < 8 * K1V) {                // 136 stagers: (l,k) = tid
    int l = tid / K1V, k = tid % K1V;
    long gi = (long)n0 * K1V + tid;   // == (n0+l)*K1V + k
    v4f w4 = { 0, 0, 0, 0 };
    int idx = 0;
    if (n0 + l < N) {
      w4  = *(const v4f*)&wtab[gi * 4];
      idx = itab[gi];
    }
    *(v4f*)&wl[l][k][0] = w4;
    nl[l][k] = idx;
  } else if (tid >= 136 && tid < 136 + 8 * HV) {
    int t = tid - 136;
    int l = t >> 2, h = t & 3;
    dagl[l][h] = (n0 + l < N) ? dagtab[(long)(n0 + l) * HV + h] : 0.0f;
  }
  __syncthreads();

  int ln = tid >> 5;          // local node
  int c  = tid & 31;          // channel
  int n  = n0 + ln;
  if (n >= N) return;

  const u16* base = xp + (size_t)bt * N * COUT + c;
  float a0 = dagl[ln][0], a1 = dagl[ln][1], a2 = dagl[ln][2], a3 = dagl[ln][3];

#pragma unroll
  for (int k = 0; k < K1V; ++k) {
    int   idx = nl[ln][k];
    float v   = bf2f(base[(size_t)idx * COUT]);
    v4f w4 = *(const v4f*)&wl[ln][k][0];
    a0 = fmaf(w4.x, v, a0);
    a1 = fmaf(w4.y, v, a1);
    a2 = fmaf(w4.z, v, a2);
    a3 = fmaf(w4.w, v, a3);
  }

  float* ob = out + (((size_t)bt * N + n) * HV) * COUT + c;
  __builtin_nontemporal_store(a0, ob);
  __builtin_nontemporal_store(a1, ob + COUT);
  __builtin_nontemporal_store(a2, ob + 2 * COUT);
  __builtin_nontemporal_store(a3, ob + 3 * COUT);
}

extern "C" void kernel_launch(void* const* d_in, const int* in_sizes, int n_in,
                              void* d_out, int out_size, void* d_ws, size_t ws_size,
                              hipStream_t stream) {
  const float* x    = (const float*)d_in[0];
  const float* W    = (const float*)d_in[1];
  const float* b    = (const float*)d_in[2];
  const float* dist = (const float*)d_in[3];
  const int*   nn   = (const int*)d_in[4];
  float* out = (float*)d_out;

  int  N  = in_sizes[4] / K1V;                 // 10000
  long M  = (long)in_sizes[0] / CIN;           // BT * N = 240000
  int  BT = (int)(M / N);                      // 24

  // workspace layout (256B-aligned): xp16 | wtab | itab | dagtab  (~19 MB)
  char* ws = (char*)d_ws;
  size_t off = 0;
  u16* xp = (u16*)(ws + off);
  off += (size_t)M * COUT * sizeof(u16);        off = (off + 255) & ~(size_t)255;
  float* wtab = (float*)(ws + off);
  off += (size_t)N * K1V * 4 * sizeof(float);   off = (off + 255) & ~(size_t)255;
  int* itab = (int*)(ws + off);
  off += (size_t)N * K1V * sizeof(int);         off = (off + 255) & ~(size_t)255;
  float* dagtab = (float*)(ws + off);

  int ngroups = (N + 7) / 8;                    // 1250

  table_kernel<<<ngroups, 256, 0, stream>>>(dist, nn, wtab, itab, dagtab, N);
  proj_kernel<<<(int)((M + RPB - 1) / RPB), 256, 0, stream>>>(x, W, b, xp, M);

  dim3 grid(ngroups, BT);                       // 1250 x 24, x fastest
  gcn_kernel<<<grid, 256, 0, stream>>>(xp, wtab, itab, dagtab, out, N);
}